// Round 1
// baseline (293.306 us; speedup 1.0000x reference)
//
#include <hip/hip_runtime.h>
#include <hip/hip_bf16.h>
#include <cstdint>
#include <cstddef>

#define T_SEQ 2048
#define CDIM  2048
#define HQ    16
#define HKV   4
#define DHEAD 128
#define NQKV  3072   // q(2048) | k(512) | v(512)

typedef __bf16 bf8 __attribute__((ext_vector_type(8)));
typedef __bf16 bf4 __attribute__((ext_vector_type(4)));
typedef float  f4  __attribute__((ext_vector_type(4)));

static __device__ __forceinline__ f4 mfma16(bf8 a, bf8 b, f4 c) {
    return __builtin_amdgcn_mfma_f32_16x16x32_bf16(a, b, c, 0, 0, 0);
}

static __device__ __forceinline__ float toF(float v) { return v; }
static __device__ __forceinline__ float toF(__bf16 v) { return (float)v; }

// ---------------- fp32 -> bf16 elementwise (x) ----------------
__global__ __launch_bounds__(256) void k_cvt(const float* __restrict__ in,
                                             __bf16* __restrict__ out, int n4) {
    int i = blockIdx.x * 256 + threadIdx.x;
    if (i >= n4) return;
    float4 v = ((const float4*)in)[i];
    bf4 o;
    o[0] = (__bf16)v.x; o[1] = (__bf16)v.y; o[2] = (__bf16)v.z; o[3] = (__bf16)v.w;
    ((bf4*)out)[i] = o;
}

// ---------------- transpose + convert: dst[c][r] = src[r][c] ----------------
template <typename TS>
__global__ __launch_bounds__(256) void k_tpose(const TS* __restrict__ src, int ld_src,
                                               __bf16* __restrict__ dst, int ld_dst,
                                               int R, int C) {
    __shared__ float tile[32][33];
    const int c0 = blockIdx.x * 32, r0 = blockIdx.y * 32;
    const int tx = threadIdx.x, ty = threadIdx.y;
#pragma unroll
    for (int i = 0; i < 4; ++i)
        tile[ty + i * 8][tx] = toF(src[(size_t)(r0 + ty + i * 8) * ld_src + c0 + tx]);
    __syncthreads();
#pragma unroll
    for (int i = 0; i < 4; ++i)
        dst[(size_t)(c0 + ty + i * 8) * ld_dst + r0 + tx] = (__bf16)tile[tx][ty + i * 8];
}

// ---------------- RoPE cos/sin table [T][64][2] ----------------
__global__ __launch_bounds__(256) void k_rtab(float* __restrict__ tab) {
    int idx = blockIdx.x * 256 + threadIdx.x;  // T*64
    int t = idx >> 6, j = idx & 63;
    float invf = expf(-(float)j * (9.210340371976184f / 64.0f));  // 10000^(-j/64)
    float a = (float)t * invf;
    tab[idx * 2 + 0] = cosf(a);
    tab[idx * 2 + 1] = sinf(a);
}

// ---------------- RoPE apply: qkv(bf16) -> Q [H][T][D], K [HKV][T][D] ----------------
__global__ __launch_bounds__(256) void k_rope(const __bf16* __restrict__ qkv,
                                              const float* __restrict__ tab,
                                              __bf16* __restrict__ Q,
                                              __bf16* __restrict__ K) {
    int idx = blockIdx.x * 256 + threadIdx.x;  // T * 20 * 64
    int j = idx & 63;
    int hd = (idx >> 6) % 20;
    int t = idx / (20 * 64);
    const __bf16* base;
    __bf16* dst;
    if (hd < HQ) {
        base = qkv + (size_t)t * NQKV + hd * DHEAD;
        dst = Q + ((size_t)hd * T_SEQ + t) * DHEAD;
    } else {
        int kvh = hd - HQ;
        base = qkv + (size_t)t * NQKV + CDIM + kvh * DHEAD;
        dst = K + ((size_t)kvh * T_SEQ + t) * DHEAD;
    }
    float a = (float)base[j], b = (float)base[j + 64];
    float c = tab[(t * 64 + j) * 2 + 0];
    float s = tab[(t * 64 + j) * 2 + 1];
    dst[j] = (__bf16)(a * c - b * s);
    dst[j + 64] = (__bf16)(b * c + a * s);
}

// ---------------- GEMM: C[M][N] = A[M][K] * BT[N][K]^T (bf16 in, fp32 acc) ----------------
template <bool OBF>
__global__ __launch_bounds__(256) void k_gemm_bt(const __bf16* __restrict__ A,
                                                 const __bf16* __restrict__ BT,
                                                 void* __restrict__ C,
                                                 int M, int N, int K, int ldc) {
    __shared__ __bf16 Al[128][40];  // 32 K-elems + pad, 80B row (16B-aligned)
    __shared__ __bf16 Bl[128][40];
    const int tid = threadIdx.x;
    const int wid = tid >> 6, lane = tid & 63;
    const int l15 = lane & 15, lhi = lane >> 4;
    const int wr = wid >> 1, wc = wid & 1;
    const size_t arow0 = (size_t)blockIdx.y * 128;
    const size_t brow0 = (size_t)blockIdx.x * 128;
    f4 acc[4][4] = {};
    const int r_st = tid >> 2, c_st = (tid & 3) * 8;

    for (int k0 = 0; k0 < K; k0 += 32) {
        *(bf8*)&Al[r_st][c_st]      = *(const bf8*)&A[(arow0 + r_st) * K + k0 + c_st];
        *(bf8*)&Al[r_st + 64][c_st] = *(const bf8*)&A[(arow0 + r_st + 64) * K + k0 + c_st];
        *(bf8*)&Bl[r_st][c_st]      = *(const bf8*)&BT[(brow0 + r_st) * K + k0 + c_st];
        *(bf8*)&Bl[r_st + 64][c_st] = *(const bf8*)&BT[(brow0 + r_st + 64) * K + k0 + c_st];
        __syncthreads();
        bf8 af[4], bfr[4];
#pragma unroll
        for (int m = 0; m < 4; ++m) af[m] = *(const bf8*)&Al[wr * 64 + m * 16 + l15][lhi * 8];
#pragma unroll
        for (int n = 0; n < 4; ++n) bfr[n] = *(const bf8*)&Bl[wc * 64 + n * 16 + l15][lhi * 8];
#pragma unroll
        for (int m = 0; m < 4; ++m)
#pragma unroll
            for (int n = 0; n < 4; ++n)
                acc[m][n] = mfma16(af[m], bfr[n], acc[m][n]);
        __syncthreads();
    }

    const int row0 = blockIdx.y * 128 + wr * 64, col0 = blockIdx.x * 128 + wc * 64;
#pragma unroll
    for (int m = 0; m < 4; ++m)
#pragma unroll
        for (int n = 0; n < 4; ++n)
#pragma unroll
            for (int j = 0; j < 4; ++j) {
                int r = row0 + m * 16 + lhi * 4 + j;
                int c = col0 + n * 16 + l15;
                float v = acc[m][n][j];
                if (OBF)
                    ((__bf16*)C)[(size_t)r * ldc + c] = (__bf16)v;
                else
                    ((float*)C)[(size_t)r * ldc + c] = v;
            }
}

// ---------------- dual-softmax flash attention ----------------
// block: (head, 64 queries), 4 waves x 16q. K-tiles of 32.
__global__ __launch_bounds__(256) void k_attn(const __bf16* __restrict__ Q,
                                              const __bf16* __restrict__ Kr,
                                              const __bf16* __restrict__ VT,
                                              __bf16* __restrict__ att) {
    __shared__ __bf16 Kl[32][136];      // [key][128d + pad], 272B rows
    __shared__ __bf16 Vl[128][40];      // [d][32k + pad], 80B rows
    __shared__ __bf16 Pl[4][16][40];    // per-wave P tile [16q][32k + pad]
    const int h = blockIdx.y, qt = blockIdx.x;
    const int kvh = h >> 2;
    const int tid = threadIdx.x, wid = tid >> 6, lane = tid & 63;
    const int l15 = lane & 15, lhi = lane >> 4;
    const int q0w = qt * 64 + wid * 16;

    bf8 qf[4];
#pragma unroll
    for (int dc = 0; dc < 4; ++dc)
        qf[dc] = *(const bf8*)&Q[((size_t)h * T_SEQ + q0w + l15) * DHEAD + dc * 32 + lhi * 8];

    f4 og[8] = {}, ol[8] = {};
    float mg[4], sg[4], ml[4], sl[4];
#pragma unroll
    for (int j = 0; j < 4; ++j) { mg[j] = ml[j] = -3.0e38f; sg[j] = sl[j] = 0.f; }

    const int iblk = (qt / 4) * 256;
    const int kst = iblk >= 128 ? iblk - 128 : 0;
    const int off = iblk - kst;
    const int ntiles = (qt + 1) * 2;
    const float scale = 0.08838834764831845f;  // 1/sqrt(128)
    const float L2E = 1.44269504088896340736f;

    for (int kt = 0; kt < ntiles; ++kt) {
        const int kb = kt * 32;
#pragma unroll
        for (int i = 0; i < 2; ++i) {
            int ch = tid + i * 256, r = ch >> 4, c2 = (ch & 15) * 8;
            *(bf8*)&Kl[r][c2] = *(const bf8*)&Kr[((size_t)kvh * T_SEQ + kb + r) * DHEAD + c2];
        }
#pragma unroll
        for (int i = 0; i < 2; ++i) {
            int ch = tid + i * 256, d = ch >> 2, c2 = (ch & 3) * 8;
            *(bf8*)&Vl[d][c2] = *(const bf8*)&VT[((size_t)kvh * DHEAD + d) * T_SEQ + kb + c2];
        }
        __syncthreads();

        const int qmaxw = q0w + 15;
        if (kb <= qmaxw) {
            f4 sc[2] = {};
#pragma unroll
            for (int dc = 0; dc < 4; ++dc) {
                bf8 k0f = *(const bf8*)&Kl[l15][dc * 32 + lhi * 8];
                sc[0] = mfma16(qf[dc], k0f, sc[0]);
            }
#pragma unroll
            for (int dc = 0; dc < 4; ++dc) {
                bf8 k1f = *(const bf8*)&Kl[16 + l15][dc * 32 + lhi * 8];
                sc[1] = mfma16(qf[dc], k1f, sc[1]);
            }
            // ---- global (causal) branch ----
            {
                float p0a[4], p1a[4];
#pragma unroll
                for (int j = 0; j < 4; ++j) {
                    int q = q0w + lhi * 4 + j;
                    float s0 = (kb + l15 <= q) ? sc[0][j] * scale : -3.0e38f;
                    float s1 = (kb + 16 + l15 <= q) ? sc[1][j] * scale : -3.0e38f;
                    float m2 = fmaxf(s0, s1);
#pragma unroll
                    for (int x = 1; x < 16; x <<= 1) m2 = fmaxf(m2, __shfl_xor(m2, x));
                    float mn = fmaxf(mg[j], m2);
                    float mun = fmaxf(mn, -1.0e30f);
                    float muo = fmaxf(mg[j], -1.0e30f);
                    float f = exp2f((muo - mun) * L2E);
                    mg[j] = mn;
                    float p0 = exp2f((s0 - mun) * L2E);
                    float p1 = exp2f((s1 - mun) * L2E);
                    float rs = p0 + p1;
#pragma unroll
                    for (int x = 1; x < 16; x <<= 1) rs += __shfl_xor(rs, x);
                    sg[j] = sg[j] * f + rs;
#pragma unroll
                    for (int nd = 0; nd < 8; ++nd) og[nd][j] *= f;
                    p0a[j] = p0; p1a[j] = p1;
                }
#pragma unroll
                for (int j = 0; j < 4; ++j) {
                    Pl[wid][lhi * 4 + j][l15] = (__bf16)p0a[j];
                    Pl[wid][lhi * 4 + j][16 + l15] = (__bf16)p1a[j];
                }
                bf8 pf = *(const bf8*)&Pl[wid][l15][lhi * 8];
#pragma unroll
                for (int nd = 0; nd < 8; ++nd) {
                    bf8 vf = *(const bf8*)&Vl[nd * 16 + l15][lhi * 8];
                    og[nd] = mfma16(pf, vf, og[nd]);
                }
            }
            // ---- local (window) branch ----
            if (kb <= qmaxw - off && kb + 31 >= kst) {
                float p0a[4], p1a[4];
#pragma unroll
                for (int j = 0; j < 4; ++j) {
                    int q = q0w + lhi * 4 + j;
                    int up = q - off;
                    int kc0 = kb + l15, kc1 = kb + 16 + l15;
                    float s0 = (kc0 >= kst && kc0 <= up) ? sc[0][j] * scale : -3.0e38f;
                    float s1 = (kc1 >= kst && kc1 <= up) ? sc[1][j] * scale : -3.0e38f;
                    float m2 = fmaxf(s0, s1);
#pragma unroll
                    for (int x = 1; x < 16; x <<= 1) m2 = fmaxf(m2, __shfl_xor(m2, x));
                    float mn = fmaxf(ml[j], m2);
                    float mun = fmaxf(mn, -1.0e30f);
                    float muo = fmaxf(ml[j], -1.0e30f);
                    float f = exp2f((muo - mun) * L2E);
                    ml[j] = mn;
                    float p0 = exp2f((s0 - mun) * L2E);
                    float p1 = exp2f((s1 - mun) * L2E);
                    float rs = p0 + p1;
#pragma unroll
                    for (int x = 1; x < 16; x <<= 1) rs += __shfl_xor(rs, x);
                    sl[j] = sl[j] * f + rs;
#pragma unroll
                    for (int nd = 0; nd < 8; ++nd) ol[nd][j] *= f;
                    p0a[j] = p0; p1a[j] = p1;
                }
#pragma unroll
                for (int j = 0; j < 4; ++j) {
                    Pl[wid][lhi * 4 + j][l15] = (__bf16)p0a[j];
                    Pl[wid][lhi * 4 + j][16 + l15] = (__bf16)p1a[j];
                }
                bf8 pf = *(const bf8*)&Pl[wid][l15][lhi * 8];
#pragma unroll
                for (int nd = 0; nd < 8; ++nd) {
                    bf8 vf = *(const bf8*)&Vl[nd * 16 + l15][lhi * 8];
                    ol[nd] = mfma16(pf, vf, ol[nd]);
                }
            }
        }
        __syncthreads();
    }

#pragma unroll
    for (int nd = 0; nd < 8; ++nd)
#pragma unroll
        for (int j = 0; j < 4; ++j) {
            int q = q0w + lhi * 4 + j;
            float v = 0.5f * (og[nd][j] / sg[j] + ol[nd][j] / sl[j]);
            att[(size_t)q * CDIM + h * DHEAD + nd * 16 + l15] = (__bf16)v;
        }
}

// ---------------- launcher ----------------
extern "C" void kernel_launch(void* const* d_in, const int* in_sizes, int n_in,
                              void* d_out, int out_size, void* d_ws, size_t ws_size,
                              hipStream_t stream) {
    const float* x  = (const float*)d_in[0];
    const float* wq = (const float*)d_in[1];
    const float* wk = (const float*)d_in[2];
    const float* wv = (const float*)d_in[3];
    const float* wo = (const float*)d_in[4];
    char* ws = (char*)d_ws;

    __bf16* xbf   = (__bf16*)(ws + 0);          // 8 MB
    __bf16* wqkvT = (__bf16*)(ws + 8388608);    // 12 MB  [3072][2048]
    __bf16* woT   = (__bf16*)(ws + 20971520);   // 8 MB   [2048][2048]
    __bf16* qkv   = (__bf16*)(ws + 29360128);   // 12 MB  [2048][3072]
    __bf16* Q     = (__bf16*)(ws + 41943040);   // 8 MB   [16][2048][128]
    __bf16* K     = (__bf16*)(ws + 50331648);   // 2 MB   [4][2048][128]
    __bf16* VT    = (__bf16*)(ws + 52428800);   // 2 MB   [4][128][2048]
    __bf16* att   = (__bf16*)(ws + 54525952);   // 8 MB   [2048][2048]
    float*  tab   = (float*)(ws + 62914560);    // 1 MB   [2048][64][2]

    k_cvt<<<4096, 256, 0, stream>>>(x, xbf, 1048576);
    k_tpose<float><<<dim3(64, 64), dim3(32, 8), 0, stream>>>(wq, 2048, wqkvT, 2048, 2048, 2048);
    k_tpose<float><<<dim3(16, 64), dim3(32, 8), 0, stream>>>(wk, 512, wqkvT + (size_t)2048 * 2048, 2048, 2048, 512);
    k_tpose<float><<<dim3(16, 64), dim3(32, 8), 0, stream>>>(wv, 512, wqkvT + (size_t)2560 * 2048, 2048, 2048, 512);
    k_tpose<float><<<dim3(64, 64), dim3(32, 8), 0, stream>>>(wo, 2048, woT, 2048, 2048, 2048);
    k_rtab<<<512, 256, 0, stream>>>(tab);
    k_gemm_bt<true><<<dim3(24, 16), 256, 0, stream>>>(xbf, wqkvT, qkv, 2048, 3072, 2048, 3072);
    k_rope<<<10240, 256, 0, stream>>>(qkv, tab, Q, K);
    k_tpose<__bf16><<<dim3(16, 64), dim3(32, 8), 0, stream>>>(qkv + 2560, 3072, VT, 2048, 2048, 512);
    k_attn<<<dim3(32, 16), 256, 0, stream>>>(Q, K, VT, att);
    k_gemm_bt<false><<<dim3(16, 16), 256, 0, stream>>>(att, woT, d_out, 2048, 2048, 2048, 2048);
}